// Round 12
// baseline (176.814 us; speedup 1.0000x reference)
//
#include <hip/hip_runtime.h>
#include <hip/hip_bf16.h>
#include <stdint.h>

#define MDIM 16384   // B*S = 4*4096
#define NDIM 2048    // MAX_OUT
#define KDIM 2048    // MAX_IN

typedef __attribute__((ext_vector_type(4)))  float f32x4;
typedef __attribute__((ext_vector_type(16))) float f32x16;
typedef __attribute__((ext_vector_type(8)))  short s16x8;

__device__ __forceinline__ void gload_lds16(const __hip_bfloat16* g, void* l) {
    __builtin_amdgcn_global_load_lds(
        (const __attribute__((address_space(1))) void*)g,
        (__attribute__((address_space(3))) void*)l,
        16, 0, 0);
}

// ---------------- prep kernels (at HBM BW floor) ----------------

__global__ __launch_bounds__(256) void prep_x(
    const float* __restrict__ x, const float* __restrict__ weights,
    const float* __restrict__ a_scales, __hip_bfloat16* __restrict__ xq)
{
    float A0 = 0.f, A1 = 0.f;
    #pragma unroll
    for (int k = 0; k < 16; ++k) {
        float w = weights[k];
        if (((k >> 1) & 1) == 0) A0 += w; else A1 += w;
    }
    const float s0 = a_scales[0], s1 = a_scales[1];
    const float r0 = 1.f / s0, r1 = 1.f / s1;

    size_t idx = ((size_t)blockIdx.x * 256 + threadIdx.x) * 8;
    const f32x4* xv = (const f32x4*)(x + idx);
    f32x4 v0 = xv[0], v1 = xv[1];
    float vals[8] = {v0.x, v0.y, v0.z, v0.w, v1.x, v1.y, v1.z, v1.w};

    union { s16x8 v; __hip_bfloat16 h[8]; } u;
    #pragma unroll
    for (int j = 0; j < 8; ++j) {
        float q0 = rintf(fminf(fmaxf(vals[j] * r0, -8.f),   7.f)) * s0;
        float q1 = rintf(fminf(fmaxf(vals[j] * r1, -128.f), 127.f)) * s1;
        u.h[j] = __float2bfloat16(A0 * q0 + A1 * q1);
    }
    *(s16x8*)(xq + idx) = u.v;
}

__global__ __launch_bounds__(256) void prep_w(
    const float* __restrict__ W, const float* __restrict__ weights,
    const float* __restrict__ w_scales, __hip_bfloat16* __restrict__ wq)
{
    float c00 = weights[0] + weights[2]  + weights[4]  + weights[6];
    float c01 = weights[1] + weights[3]  + weights[5]  + weights[7];
    float c10 = weights[8] + weights[10] + weights[12] + weights[14];
    float c11 = weights[9] + weights[11] + weights[13] + weights[15];

    const float s0 = w_scales[0], s1 = w_scales[1];
    const float r0 = 1.f / s0, r1 = 1.f / s1;

    size_t idx = ((size_t)blockIdx.x * 256 + threadIdx.x) * 8;
    const int o = (int)(idx >> 11);
    const int c = (int)(idx & 2047);
    const bool inner = (o < 1024) && (c < 1024);
    const float k0 = inner ? (c00 + c10) : c10;
    const float k1 = inner ? (c01 + c11) : c11;

    const f32x4* wv = (const f32x4*)(W + idx);
    f32x4 v0 = wv[0], v1 = wv[1];
    float vals[8] = {v0.x, v0.y, v0.z, v0.w, v1.x, v1.y, v1.z, v1.w};

    union { s16x8 v; __hip_bfloat16 h[8]; } u;
    #pragma unroll
    for (int j = 0; j < 8; ++j) {
        float q0 = rintf(fminf(fmaxf(vals[j] * r0, -8.f),   7.f)) * s0;
        float q1 = rintf(fminf(fmaxf(vals[j] * r1, -128.f), 127.f)) * s1;
        u.h[j] = __float2bfloat16(k0 * q0 + k1 * q1);
    }
    *(s16x8*)(wq + idx) = u.v;
}

__global__ __launch_bounds__(256) void prep_b(
    const float* __restrict__ b, const float* __restrict__ weights,
    float* __restrict__ bm)
{
    int o = blockIdx.x * 256 + threadIdx.x;
    if (o >= NDIM) return;
    float S1 = 0.f, S0 = 0.f;
    #pragma unroll
    for (int k = 0; k < 8; ++k)  S0 += weights[k];
    #pragma unroll
    for (int k = 8; k < 16; ++k) S1 += weights[k];
    bm[o] = b[o] * ((o < 1024) ? (S0 + S1) : S1);
}

// ---------------- GEMM: 256x256 tile, 8 waves, ring-4 of 32-k chunks,
// R7 chunk body (best schedule family) with 32x32x16 MFMA:
// 4060 vs 3377 FLOP/cyc/CU (m119 vs m06) and HALF the MFMA instructions.
// Per wave per chunk: 8 A-frag + 4 B-frag ds_read_b128, 16 MFMA.
// Counted vmcnt(8) + 1 raw barrier per chunk; T1 + T2 swizzles. ----

#define NCH 64           // K chunks of 32
#define ASLOT 16384      // bytes per A slot (256 rows x 64 B)
#define BREG  65536      // B region base (4 A slots first)

#define MFMA32(a, b, c) __builtin_amdgcn_mfma_f32_32x32x16_bf16((a), (b), (c), 0, 0, 0)

// S = c&3 (compute slot), T = (c+3)&3 (stage slot).
#define CHUNK(S, T)                                                          \
  {                                                                          \
    asm volatile("" ::: "memory");  /* no hoist of reads above barrier */    \
    s16x8 af[4][2], bf[2][2];                                                \
    _Pragma("unroll")                                                        \
    for (int mi_ = 0; mi_ < 4; ++mi_) {                                      \
      af[mi_][0] = *(const s16x8*)(lds + (S) * ASLOT + aoffb + mi_ * 2048 + xk0); \
      af[mi_][1] = *(const s16x8*)(lds + (S) * ASLOT + aoffb + mi_ * 2048 + xk1); \
    }                                                                        \
    _Pragma("unroll")                                                        \
    for (int ni_ = 0; ni_ < 2; ++ni_) {                                      \
      bf[ni_][0] = *(const s16x8*)(lds + BREG + (S) * ASLOT + boffb + ni_ * 2048 + xk0); \
      bf[ni_][1] = *(const s16x8*)(lds + BREG + (S) * ASLOT + boffb + ni_ * 2048 + xk1); \
    }                                                                        \
    gload_lds16(As0 + kg * 32, lds + (T) * ASLOT + ldoff);                   \
    gload_lds16(As1 + kg * 32, lds + (T) * ASLOT + 8192 + ldoff);            \
    gload_lds16(Bs0 + kg * 32, lds + BREG + (T) * ASLOT + ldoff);            \
    gload_lds16(Bs1 + kg * 32, lds + BREG + (T) * ASLOT + 8192 + ldoff);     \
    kg = (kg + 1) & (NCH - 1);                                               \
    __builtin_amdgcn_s_setprio(1);                                           \
    _Pragma("unroll")                                                        \
    for (int mi_ = 0; mi_ < 4; ++mi_) {                                      \
      acc[mi_][0] = MFMA32(af[mi_][0], bf[0][0], acc[mi_][0]);               \
      acc[mi_][0] = MFMA32(af[mi_][1], bf[0][1], acc[mi_][0]);               \
      acc[mi_][1] = MFMA32(af[mi_][0], bf[1][0], acc[mi_][1]);               \
      acc[mi_][1] = MFMA32(af[mi_][1], bf[1][1], acc[mi_][1]);               \
    }                                                                        \
    __builtin_amdgcn_s_setprio(0);                                           \
    asm volatile("s_waitcnt vmcnt(8)" ::: "memory");  /* chunk c+1 landed */ \
    __builtin_amdgcn_s_barrier();                                            \
  }

__global__ __launch_bounds__(512, 2) void gemm256(
    const __hip_bfloat16* __restrict__ A,
    const __hip_bfloat16* __restrict__ B,
    const float* __restrict__ bias,
    float* __restrict__ C)
{
    __shared__ char lds[8 * ASLOT];   // 128 KiB: A slots 0-3, B slots 0-3

    const int tid  = threadIdx.x;
    const int lane = tid & 63;
    const int wid  = tid >> 6;    // 0..7
    const int wm   = wid >> 2;    // 0..1  (M half)
    const int wn   = wid & 3;     // 0..3  (N quarter)

    // T1 (measured FETCH ~104 MB): XCD = bid%8 owns 8 row-panels x 8 cols.
    const int bid  = blockIdx.x;
    const int swz  = (bid & 7) * 64 + (bid >> 3);
    const int brow = (swz >> 3) * 256;
    const int bcol = (swz & 7) * 256;

    // ---- staging: linear LDS dest, pre-swizzled global source (T2) ----
    // thread t writes 16B at slot-offset t*16 (row t>>2, phys k-slot t&3);
    // logical k-slot = (t&3) ^ ((row>>1)&3).  (measured: 0 bank conflicts)
    const int csw = (tid & 3) ^ ((tid >> 3) & 3);
    const __hip_bfloat16* As0 = A + (size_t)(brow + (tid >> 2)) * KDIM + csw * 8;
    const __hip_bfloat16* As1 = As0 + (size_t)128 * KDIM;
    const __hip_bfloat16* Bs0 = B + (size_t)(bcol + (tid >> 2)) * KDIM + csw * 8;
    const __hip_bfloat16* Bs1 = Bs0 + (size_t)128 * KDIM;
    const int ldoff = tid * 16;

    // ---- 32x32 fragment-read constants ----
    // Operand: lane l holds X[row=l&31][k = 8*(l>>5) + j].  Read addr =
    // (rowbase + arow)*64 + swz_slot*16, swz_slot = (kk*2 + kh5) ^ axor.
    const int arow = lane & 31;
    const int kh5  = lane >> 5;
    const int axor = (arow >> 1) & 3;
    const int xk0  = ((0 + kh5) ^ axor) * 16;   // kk = 0
    const int xk1  = ((2 + kh5) ^ axor) * 16;   // kk = 1
    const int aoffb = (wm * 128 + arow) * 64;   // + mi*2048
    const int boffb = (wn * 64  + arow) * 64;   // + ni*2048

    f32x16 acc[4][2];
    #pragma unroll
    for (int mi = 0; mi < 4; ++mi)
        #pragma unroll
        for (int ni = 0; ni < 2; ++ni)
            acc[mi][ni] = (f32x16){0.f,0.f,0.f,0.f,0.f,0.f,0.f,0.f,
                                   0.f,0.f,0.f,0.f,0.f,0.f,0.f,0.f};

    int kg = 3;   // chunk index to stage next

    // ---- prologue: stage chunks 0,1,2 (oldest-first); gate chunk 0 ----
    #pragma unroll
    for (int q = 0; q < 3; ++q) {
        gload_lds16(As0 + q * 32, lds + q * ASLOT + ldoff);
        gload_lds16(As1 + q * 32, lds + q * ASLOT + 8192 + ldoff);
        gload_lds16(Bs0 + q * 32, lds + BREG + q * ASLOT + ldoff);
        gload_lds16(Bs1 + q * 32, lds + BREG + q * ASLOT + 8192 + ldoff);
    }
    asm volatile("s_waitcnt vmcnt(8)" ::: "memory");  // chunk 0 landed
    __builtin_amdgcn_s_barrier();

    #pragma unroll 1
    for (int it = 0; it < NCH / 4; ++it) {
        CHUNK(0, 3);   // chunk 4it
        CHUNK(1, 0);   // chunk 4it+1
        CHUNK(2, 1);   // chunk 4it+2
        CHUNK(3, 2);   // chunk 4it+3
    }
    asm volatile("s_waitcnt vmcnt(0) lgkmcnt(0)" ::: "memory");

    // ---- epilogue: 32x32 C/D layout [m74/m101]:
    // col = lane&31, row = (reg&3) + 8*(reg>>2) + 4*(lane>>5) ----
    const int ccol0 = bcol + wn * 64 + arow;
    const int crow0 = brow + wm * 128 + kh5 * 4;
    float bv[2];
    #pragma unroll
    for (int ni = 0; ni < 2; ++ni) bv[ni] = bias[ccol0 + ni * 32];

    #pragma unroll
    for (int mi = 0; mi < 4; ++mi) {
        #pragma unroll
        for (int r = 0; r < 16; ++r) {
            const int row = crow0 + mi * 32 + (r & 3) + 8 * (r >> 2);
            float* Crow = C + (size_t)row * NDIM;
            Crow[ccol0]      = acc[mi][0][r] + bv[0];
            Crow[ccol0 + 32] = acc[mi][1][r] + bv[1];
        }
    }
}

// ---------------- launcher ----------------

extern "C" void kernel_launch(void* const* d_in, const int* in_sizes, int n_in,
                              void* d_out, int out_size, void* d_ws, size_t ws_size,
                              hipStream_t stream) {
    const float* x        = (const float*)d_in[0];  // [4,4096,2048]
    const float* weights  = (const float*)d_in[1];  // [16]
    const float* W        = (const float*)d_in[2];  // [2048,2048]
    const float* b        = (const float*)d_in[3];  // [2048]
    const float* a_scales = (const float*)d_in[4];  // [2]
    const float* w_scales = (const float*)d_in[5];  // [2]
    float* out = (float*)d_out;

    __hip_bfloat16* xq = (__hip_bfloat16*)d_ws;                            // 67108864 B
    __hip_bfloat16* wq = (__hip_bfloat16*)((char*)d_ws + 67108864);        //  8388608 B
    float*          bm = (float*)((char*)d_ws + 67108864 + 8388608);       //     8192 B

    prep_w<<<dim3((NDIM * KDIM) / (256 * 8)), dim3(256), 0, stream>>>(W, weights, w_scales, wq);
    prep_b<<<dim3(NDIM / 256), dim3(256), 0, stream>>>(b, weights, bm);
    prep_x<<<dim3(((size_t)MDIM * KDIM) / (256 * 8)), dim3(256), 0, stream>>>(x, weights, a_scales, xq);
    gemm256<<<dim3((MDIM / 256) * (NDIM / 256)), dim3(512), 0, stream>>>(xq, wq, bm, out);
}

// Round 13
// 157.018 us; speedup vs baseline: 1.1261x; 1.1261x over previous
//
#include <hip/hip_runtime.h>
#include <hip/hip_bf16.h>
#include <stdint.h>

#define MDIM 16384   // B*S = 4*4096
#define NDIM 2048    // MAX_OUT
#define KDIM 2048    // MAX_IN

typedef __attribute__((ext_vector_type(4))) float f32x4;
typedef __attribute__((ext_vector_type(8))) short s16x8;

__device__ __forceinline__ void gload_lds16(const __hip_bfloat16* g, void* l) {
    __builtin_amdgcn_global_load_lds(
        (const __attribute__((address_space(1))) void*)g,
        (__attribute__((address_space(3))) void*)l,
        16, 0, 0);
}

// ---------------- fused prep kernel (one launch, three block ranges) --------
// blocks [0, 16384): x-mix quantize (192 MB traffic, HBM floor)
// blocks [16384, 18432): w-mix quantize (10 MB)
// blocks [18432, 18440): bias mix
#define XBLKS 16384
#define WBLKS 2048

__global__ __launch_bounds__(256) void prep_all(
    const float* __restrict__ x, const float* __restrict__ weights,
    const float* __restrict__ W, const float* __restrict__ b,
    const float* __restrict__ a_scales, const float* __restrict__ w_scales,
    __hip_bfloat16* __restrict__ xq, __hip_bfloat16* __restrict__ wq,
    float* __restrict__ bm)
{
    const int blk = blockIdx.x;
    if (blk < XBLKS) {
        // ---- x_mix = A0*fq(x,s0,4) + A1*fq(x,s1,8), stored bf16 ----
        float A0 = 0.f, A1 = 0.f;
        #pragma unroll
        for (int k = 0; k < 16; ++k) {
            float w = weights[k];
            if (((k >> 1) & 1) == 0) A0 += w; else A1 += w;
        }
        const float s0 = a_scales[0], s1 = a_scales[1];
        const float r0 = 1.f / s0, r1 = 1.f / s1;

        size_t idx = ((size_t)blk * 256 + threadIdx.x) * 8;
        const f32x4* xv = (const f32x4*)(x + idx);
        f32x4 v0 = xv[0], v1 = xv[1];
        float vals[8] = {v0.x, v0.y, v0.z, v0.w, v1.x, v1.y, v1.z, v1.w};

        union { s16x8 v; __hip_bfloat16 h[8]; } u;
        #pragma unroll
        for (int j = 0; j < 8; ++j) {
            float q0 = rintf(fminf(fmaxf(vals[j] * r0, -8.f),   7.f)) * s0;
            float q1 = rintf(fminf(fmaxf(vals[j] * r1, -128.f), 127.f)) * s1;
            u.h[j] = __float2bfloat16(A0 * q0 + A1 * q1);
        }
        *(s16x8*)(xq + idx) = u.v;
    } else if (blk < XBLKS + WBLKS) {
        // ---- w_mix: region-coefficient quantized mix, stored bf16 ----
        float c00 = weights[0] + weights[2]  + weights[4]  + weights[6];
        float c01 = weights[1] + weights[3]  + weights[5]  + weights[7];
        float c10 = weights[8] + weights[10] + weights[12] + weights[14];
        float c11 = weights[9] + weights[11] + weights[13] + weights[15];

        const float s0 = w_scales[0], s1 = w_scales[1];
        const float r0 = 1.f / s0, r1 = 1.f / s1;

        size_t idx = ((size_t)(blk - XBLKS) * 256 + threadIdx.x) * 8;
        const int o = (int)(idx >> 11);
        const int c = (int)(idx & 2047);
        const bool inner = (o < 1024) && (c < 1024);
        const float k0 = inner ? (c00 + c10) : c10;
        const float k1 = inner ? (c01 + c11) : c11;

        const f32x4* wv = (const f32x4*)(W + idx);
        f32x4 v0 = wv[0], v1 = wv[1];
        float vals[8] = {v0.x, v0.y, v0.z, v0.w, v1.x, v1.y, v1.z, v1.w};

        union { s16x8 v; __hip_bfloat16 h[8]; } u;
        #pragma unroll
        for (int j = 0; j < 8; ++j) {
            float q0 = rintf(fminf(fmaxf(vals[j] * r0, -8.f),   7.f)) * s0;
            float q1 = rintf(fminf(fmaxf(vals[j] * r1, -128.f), 127.f)) * s1;
            u.h[j] = __float2bfloat16(k0 * q0 + k1 * q1);
        }
        *(s16x8*)(wq + idx) = u.v;
    } else {
        // ---- b_mix ----
        int o = (blk - XBLKS - WBLKS) * 256 + threadIdx.x;
        if (o < NDIM) {
            float S1 = 0.f, S0 = 0.f;
            #pragma unroll
            for (int k = 0; k < 8; ++k)  S0 += weights[k];
            #pragma unroll
            for (int k = 8; k < 16; ++k) S1 += weights[k];
            bm[o] = b[o] * ((o < 1024) ? (S0 + S1) : S1);
        }
    }
}

// ---------------- GEMM (champion, R7/R8 body, measured 122.4 us):
// 256x256 tile, 8 waves, ring-4 of 32-k chunks. Structure the compiler
// can't derive: counted vmcnt(8) + 1 raw s_barrier per chunk + T1/T2
// swizzles + setprio. Instruction scheduling (ds_read vs MFMA interleave,
// fine lgkmcnt) left ENTIRELY to the compiler. ----

#define NCH 64           // K chunks of 32
#define ASLOT 16384      // bytes per A slot (256 rows x 64 B)
#define BREG  65536      // B region base (4 A slots first)

#define MFMA(a, b, c) __builtin_amdgcn_mfma_f32_16x16x32_bf16((a), (b), (c), 0, 0, 0)

// S = c&3 (compute slot), T = (c+3)&3 (stage slot).
#define CHUNK(S, T)                                                          \
  {                                                                          \
    asm volatile("" ::: "memory");  /* no hoist of reads above barrier */    \
    s16x8 af[8], bf[4];                                                      \
    _Pragma("unroll")                                                        \
    for (int m_ = 0; m_ < 8; ++m_)                                           \
      af[m_] = *(const s16x8*)(lds + (S) * ASLOT + aoff + m_ * 1024);        \
    _Pragma("unroll")                                                        \
    for (int n_ = 0; n_ < 4; ++n_)                                           \
      bf[n_] = *(const s16x8*)(lds + BREG + (S) * ASLOT + boff + n_ * 1024); \
    gload_lds16(As0 + kg * 32, lds + (T) * ASLOT + ldoff);                   \
    gload_lds16(As1 + kg * 32, lds + (T) * ASLOT + 8192 + ldoff);            \
    gload_lds16(Bs0 + kg * 32, lds + BREG + (T) * ASLOT + ldoff);            \
    gload_lds16(Bs1 + kg * 32, lds + BREG + (T) * ASLOT + 8192 + ldoff);     \
    kg = (kg + 1) & (NCH - 1);                                               \
    __builtin_amdgcn_s_setprio(1);                                           \
    _Pragma("unroll")                                                        \
    for (int m_ = 0; m_ < 8; ++m_) {                                         \
      acc[m_][0] = MFMA(af[m_], bf[0], acc[m_][0]);                          \
      acc[m_][1] = MFMA(af[m_], bf[1], acc[m_][1]);                          \
      acc[m_][2] = MFMA(af[m_], bf[2], acc[m_][2]);                          \
      acc[m_][3] = MFMA(af[m_], bf[3], acc[m_][3]);                          \
    }                                                                        \
    __builtin_amdgcn_s_setprio(0);                                           \
    asm volatile("s_waitcnt vmcnt(8)" ::: "memory");  /* chunk c+1 landed */ \
    __builtin_amdgcn_s_barrier();                                            \
  }

__global__ __launch_bounds__(512, 2) void gemm256(
    const __hip_bfloat16* __restrict__ A,
    const __hip_bfloat16* __restrict__ B,
    const float* __restrict__ bias,
    float* __restrict__ C)
{
    __shared__ char lds[8 * ASLOT];   // 128 KiB: A slots 0-3, B slots 0-3

    const int tid  = threadIdx.x;
    const int lane = tid & 63;
    const int wid  = tid >> 6;    // 0..7
    const int wm   = wid >> 2;    // 0..1  (M half)
    const int wn   = wid & 3;     // 0..3  (N quarter)

    // T1 (measured FETCH ~104 MB): XCD = bid%8 owns 8 row-panels x 8 cols
    // -> A panel L2-resident, B cycles L3-hot.
    const int bid  = blockIdx.x;
    const int swz  = (bid & 7) * 64 + (bid >> 3);
    const int brow = (swz >> 3) * 256;
    const int bcol = (swz & 7) * 256;

    // ---- staging: linear LDS dest, pre-swizzled global source (T2) ----
    // thread t writes 16B at slot-offset t*16 (row t>>2, phys k-slot t&3);
    // logical k-slot = (t&3) ^ ((t>>3)&3).  (measured: 0 bank conflicts)
    const int csw = (tid & 3) ^ ((tid >> 3) & 3);
    const __hip_bfloat16* As0 = A + (size_t)(brow + (tid >> 2)) * KDIM + csw * 8;
    const __hip_bfloat16* As1 = As0 + (size_t)128 * KDIM;
    const __hip_bfloat16* Bs0 = B + (size_t)(bcol + (tid >> 2)) * KDIM + csw * 8;
    const __hip_bfloat16* Bs1 = Bs0 + (size_t)128 * KDIM;
    const int ldoff = tid * 16;

    // ---- fragment-read constants (swizzle inverse; lane-constant XOR) ----
    const int fr  = lane & 15;
    const int l16 = lane >> 4;
    const int xr  = (l16 ^ ((fr >> 1) & 3)) * 16;
    const int aoff = (wm * 128 + fr) * 64 + xr;
    const int boff = (wn * 64  + fr) * 64 + xr;

    f32x4 acc[8][4];
    #pragma unroll
    for (int m = 0; m < 8; ++m)
        #pragma unroll
        for (int n = 0; n < 4; ++n)
            acc[m][n] = (f32x4){0.f, 0.f, 0.f, 0.f};

    int kg = 3;   // chunk index to stage next

    // ---- prologue: stage chunks 0,1,2 (oldest-first); gate chunk 0 ----
    #pragma unroll
    for (int q = 0; q < 3; ++q) {
        gload_lds16(As0 + q * 32, lds + q * ASLOT + ldoff);
        gload_lds16(As1 + q * 32, lds + q * ASLOT + 8192 + ldoff);
        gload_lds16(Bs0 + q * 32, lds + BREG + q * ASLOT + ldoff);
        gload_lds16(Bs1 + q * 32, lds + BREG + q * ASLOT + 8192 + ldoff);
    }
    asm volatile("s_waitcnt vmcnt(8)" ::: "memory");  // chunk 0 landed
    __builtin_amdgcn_s_barrier();

    #pragma unroll 1
    for (int it = 0; it < NCH / 4; ++it) {
        CHUNK(0, 3);   // chunk 4it
        CHUNK(1, 0);   // chunk 4it+1
        CHUNK(2, 1);   // chunk 4it+2
        CHUNK(3, 2);   // chunk 4it+3
    }
    asm volatile("s_waitcnt vmcnt(0) lgkmcnt(0)" ::: "memory");

    // ---- epilogue: C/D layout col = lane&15, row = (lane>>4)*4 + j ----
    const int ccol0 = bcol + wn * 64 + fr;
    const int crow0 = brow + wm * 128 + l16 * 4;
    float bv[4];
    #pragma unroll
    for (int n = 0; n < 4; ++n) bv[n] = bias[ccol0 + n * 16];

    #pragma unroll
    for (int m = 0; m < 8; ++m) {
        #pragma unroll
        for (int j = 0; j < 4; ++j) {
            float* Crow = C + (size_t)(crow0 + m * 16 + j) * NDIM;
            #pragma unroll
            for (int n = 0; n < 4; ++n)
                Crow[ccol0 + n * 16] = acc[m][n][j] + bv[n];
        }
    }
}

// ---------------- launcher ----------------

extern "C" void kernel_launch(void* const* d_in, const int* in_sizes, int n_in,
                              void* d_out, int out_size, void* d_ws, size_t ws_size,
                              hipStream_t stream) {
    const float* x        = (const float*)d_in[0];  // [4,4096,2048]
    const float* weights  = (const float*)d_in[1];  // [16]
    const float* W        = (const float*)d_in[2];  // [2048,2048]
    const float* b        = (const float*)d_in[3];  // [2048]
    const float* a_scales = (const float*)d_in[4];  // [2]
    const float* w_scales = (const float*)d_in[5];  // [2]
    float* out = (float*)d_out;

    __hip_bfloat16* xq = (__hip_bfloat16*)d_ws;                            // 67108864 B
    __hip_bfloat16* wq = (__hip_bfloat16*)((char*)d_ws + 67108864);        //  8388608 B
    float*          bm = (float*)((char*)d_ws + 67108864 + 8388608);       //     8192 B

    prep_all<<<dim3(XBLKS + WBLKS + 8), dim3(256), 0, stream>>>(
        x, weights, W, b, a_scales, w_scales, xq, wq, bm);
    gemm256<<<dim3((MDIM / 256) * (NDIM / 256)), dim3(512), 0, stream>>>(xq, wq, bm, out);
}